// Round 17
// baseline (55.050 us; speedup 1.0000x reference)
//
#include <hip/hip_runtime.h>
#include <hip/hip_bf16.h>

#define NROWS 8192
#define DIM 256
#define NSPLIT 16
#define JSPAN (NROWS / NSPLIT)   /* 512 cols per block */
#define TILE_COLS 64
#define TILE_BYTES (TILE_COLS * 512)  /* 32 KB */
#define NT (JSPAN / TILE_COLS)   /* 8 tiles per block */
#define RPW 64                   /* rows per wave (A stationary) */
#define RPB 512                  /* rows per block (8 waves) */
#define GRP_BYTES 8192           /* 16 cols x 512 B, K-major-grouped */

typedef __bf16 bf16x8 __attribute__((ext_vector_type(8)));
typedef float f32x4 __attribute__((ext_vector_type(4)));

#define NEG_LOG2E -1.4426950408889634f
#define NEG_LN2   -0.6931471805599453f

// ---- Kernel 1: L2-normalize rows, fp32 -> bf16; zero accums ----
// En: row-major, scaled by -log2(e) (GEMM acc = -log2e*sim; exp(-sim)=exp2(acc)).
// Qn: K-MAJOR-GROUPED. Group g = cols [16g,16g+16); chunk kk (1 KB) = the 16
// cols' 64B K-slice kk, col-interleaved at 64B.
__global__ __launch_bounds__(256) void k_normalize_all(const float* __restrict__ emb,
                                                       const float* __restrict__ qry,
                                                       __hip_bfloat16* __restrict__ En,
                                                       __hip_bfloat16* __restrict__ Qn,
                                                       float* __restrict__ rowsum,
                                                       float* __restrict__ out) {
    if (blockIdx.x < 8)
        reinterpret_cast<float4*>(rowsum)[blockIdx.x * 256 + threadIdx.x] =
            float4{0.f, 0.f, 0.f, 0.f};
    if (blockIdx.x == 8 && threadIdx.x == 0) out[0] = 0.f;

    const int gr   = blockIdx.x * 4 + (threadIdx.x >> 6);
    const int lane = threadIdx.x & 63;
    const bool isE = (gr < NROWS);
    const float* in = isE ? emb : qry;
    const int row   = isE ? gr : gr - NROWS;
    const float scale = isE ? NEG_LOG2E : 1.0f;

    const float4 v = reinterpret_cast<const float4*>(in + (size_t)row * DIM)[lane];
    float ss = v.x * v.x + v.y * v.y + v.z * v.z + v.w * v.w;
#pragma unroll
    for (int m = 32; m >= 1; m >>= 1) ss += __shfl_xor(ss, m, 64);
    const float inv = scale / fmaxf(sqrtf(ss), 1e-8f);
    __hip_bfloat16 o[4];
    o[0] = __float2bfloat16(v.x * inv);
    o[1] = __float2bfloat16(v.y * inv);
    o[2] = __float2bfloat16(v.z * inv);
    o[3] = __float2bfloat16(v.w * inv);
    const ushort4 o8 = *reinterpret_cast<const ushort4*>(o);

    if (isE) {
        reinterpret_cast<ushort4*>(En + (size_t)row * DIM)[lane] = o8;
    } else {
        const int g = row >> 4, c = row & 15;
        char* dst = (char*)Qn + (size_t)g * GRP_BYTES
                    + (size_t)(lane >> 3) * 1024 + c * 64 + (lane & 7) * 8;
        *reinterpret_cast<ushort4*>(dst) = o8;
    }
}

// ---- Kernel 2: fused sim-GEMM + row sum of exp(-s), m201-style phases ----
// 8 waves x 64 rows (a[4][8] = 128 VGPR, ~215 total -> 2 waves/SIMD, which is
// enough IF the schedule staggers them: HK runs 70%+ at 2 waves/SIMD).
// Ring-3 of 32KB tiles. Per tile, 4 phases (16-col group each):
//   { 8 ds_read ; issue 1 DMA chunk of tile t+2 ; s_barrier ;
//     lgkmcnt(0)+sched_barrier ; setprio(1) ; 32 MFMA ; setprio(0) ;
//     exp2 epilogue ; s_barrier }
// Tile boundary: counted vmcnt(4) (own tile-t+2 chunks stay in flight; only
// the tail drains to 0) before the last phase barrier -> tile t+1 resident
// block-wide. The double-barrier phases stagger the 2 resident waves:
// one reads while the other owns the matrix pipe.
__global__ __launch_bounds__(512, 2) void k_simlse(const __hip_bfloat16* __restrict__ En,
                                                   const __hip_bfloat16* __restrict__ Qn,
                                                   float* __restrict__ rowsum,
                                                   float* __restrict__ pickv) {
    __shared__ char lds[3][TILE_BYTES];   // 96 KB ring-3
    const int bx   = blockIdx.x;
    const int ib   = bx >> 4;            // 0..15
    const int jq   = bx & 15;
    const int tid  = threadIdx.x;
    const int lane = tid & 63;
    const int w    = tid >> 6;           // wave 0..7
    const int l15  = lane & 15;
    const int lks  = lane >> 4;          // k-segment 0..3
    const int i0w  = ib * RPB + w * RPW;

    // A fragments: 64 rows x K=256 -> a[4][8] (128 regs).
    bf16x8 a[4][8];
    {
        const __hip_bfloat16* ab = En + (size_t)(i0w + l15) * DIM + lks * 8;
#pragma unroll
        for (int mi = 0; mi < 4; ++mi)
#pragma unroll
            for (int kk = 0; kk < 8; ++kk)
                a[mi][kk] = *reinterpret_cast<const bf16x8*>(ab + mi * 16 * DIM + kk * 32);
    }

    float racc[4][4];
#pragma unroll
    for (int mi = 0; mi < 4; ++mi)
#pragma unroll
        for (int r = 0; r < 4; ++r) racc[mi][r] = 0.0f;

    const int jq0 = jq * JSPAN;
    // Wave w stages chunks [4w, 4w+4) of each tile, one chunk per phase.
    // Source: contiguous identity copy (K-major-grouped Qn).
    const char* qsrc = (const char*)Qn + (size_t)jq0 * 512 + (size_t)lane * 16
                       + (size_t)w * 4096;

    auto stage_chunk = [&](int t, int g, char* buf) {
        __builtin_amdgcn_global_load_lds(
            (const __attribute__((address_space(1))) void*)
                (qsrc + (size_t)t * TILE_BYTES + g * 1024),
            (__attribute__((address_space(3))) void*)(buf + w * 4096 + g * 1024),
            16, 0, 0);
    };

    // Ring pointers: b0 = tile t, b1 = t+1, b2 = t+2 (stage target).
    char* b0 = lds[0];
    char* b1 = lds[1];
    char* b2 = lds[2];

    // Prologue: stage tiles 0 and 1 fully; vmcnt(4) leaves tile 1 in flight.
#pragma unroll
    for (int g = 0; g < 4; ++g) stage_chunk(0, g, b0);
#pragma unroll
    for (int g = 0; g < 4; ++g) stage_chunk(1, g, b1);
    asm volatile("s_waitcnt vmcnt(4)" ::: "memory");
    __builtin_amdgcn_sched_barrier(0);
    __builtin_amdgcn_s_barrier();

    for (int t = 0; t < NT; ++t) {
        const char* rd = b0 + l15 * 64 + lks * 16;   // conflict-free frag base
        const int tbase = jq0 + t * TILE_COLS;
        const bool spec_t = (tbase <= i0w + RPW) && (tbase + TILE_COLS > i0w);

#pragma unroll
        for (int g = 0; g < 4; ++g) {
            // Phase g: ds_read this group's 8 fragments.
            bf16x8 b[8];
#pragma unroll
            for (int kk = 0; kk < 8; ++kk)
                b[kk] = *reinterpret_cast<const bf16x8*>(rd + (g * 8 + kk) * 1024);

            // Issue 1 DMA chunk of tile t+2 (overwrites buffer read at t-1;
            // everyone finished those reads before this tile's first barrier).
            if (t + 2 < NT) stage_chunk(t + 2, g, b2);

            __builtin_amdgcn_s_barrier();
            asm volatile("s_waitcnt lgkmcnt(0)" ::: "memory");
            __builtin_amdgcn_sched_barrier(0);

            f32x4 acc[4];
#pragma unroll
            for (int mi = 0; mi < 4; ++mi) acc[mi] = f32x4{0.f, 0.f, 0.f, 0.f};

            __builtin_amdgcn_s_setprio(1);
#pragma unroll
            for (int kk = 0; kk < 8; ++kk)
#pragma unroll
                for (int mi = 0; mi < 4; ++mi)
                    acc[mi] = __builtin_amdgcn_mfma_f32_16x16x32_bf16(
                        a[mi][kk], b[kk], acc[mi], 0, 0, 0);
            __builtin_amdgcn_s_setprio(0);

            // Epilogue. acc = -log2e*s; exp(-s) = exp2(acc).
            // C/D layout: col = lane&15, row = (lane>>4)*4 + r.
            const int grpbase = tbase + g * 16;
            const bool spec = spec_t && (grpbase <= i0w + RPW) && (grpbase + 16 > i0w);
            if (!spec) {
#pragma unroll
                for (int mi = 0; mi < 4; ++mi)
#pragma unroll
                    for (int r = 0; r < 4; ++r)
                        racc[mi][r] += __builtin_amdgcn_exp2f(acc[mi][r]);
            } else {
                const int jg = grpbase + l15;
#pragma unroll
                for (int mi = 0; mi < 4; ++mi) {
                    const int ig0 = i0w + mi * 16 + lks * 4;
#pragma unroll
                    for (int r = 0; r < 4; ++r) {
                        const float e  = __builtin_amdgcn_exp2f(acc[mi][r]);
                        const int   ig = ig0 + r;
                        racc[mi][r] += (jg == ig) ? 0.0f : e;
                        const int pc = (ig == NROWS - 1) ? (NROWS - 2) : (ig + 1);
                        if (jg == pc) pickv[ig] = acc[mi][r] * NEG_LN2;  // recover s
                    }
                }
            }

            // Last phase of a tile: counted vmcnt so tile t+1 is resident
            // block-wide after the barrier (own t+2 chunks stay in flight).
            if (g == 3 && t < NT - 1) {
                if (t + 2 < NT) asm volatile("s_waitcnt vmcnt(4)" ::: "memory");
                else            asm volatile("s_waitcnt vmcnt(0)" ::: "memory");
                __builtin_amdgcn_sched_barrier(0);
            }
            __builtin_amdgcn_s_barrier();
        }

        // Rotate ring: t+1 becomes current, old current becomes stage target.
        char* tmp = b0; b0 = b1; b1 = b2; b2 = tmp;
    }

    // Reduce row partials across the 16 col-lanes, one atomicAdd per row.
#pragma unroll
    for (int mi = 0; mi < 4; ++mi)
#pragma unroll
        for (int r = 0; r < 4; ++r) {
            float v = racc[mi][r];
            v += __shfl_xor(v, 1, 64);
            v += __shfl_xor(v, 2, 64);
            v += __shfl_xor(v, 4, 64);
            v += __shfl_xor(v, 8, 64);
            if (l15 == 0) atomicAdd(&rowsum[i0w + mi * 16 + lks * 4 + r], v);
        }
}

// ---- Kernel 3: final reduce, 16 blocks, one atomicAdd each (out pre-zeroed) ----
__global__ __launch_bounds__(256) void k_finalize(const float* __restrict__ rowsum,
                                                  const float* __restrict__ pickv,
                                                  float* __restrict__ out) {
    __shared__ float red[4];
    const int base = blockIdx.x * 512;
    float s = 0.0f;
#pragma unroll
    for (int it = 0; it < 2; ++it) {
        const int i = base + it * 256 + threadIdx.x;
        s += __logf(rowsum[i]) + pickv[i];
    }
#pragma unroll
    for (int m = 32; m >= 1; m >>= 1) s += __shfl_xor(s, m, 64);
    if ((threadIdx.x & 63) == 0) red[threadIdx.x >> 6] = s;
    __syncthreads();
    if (threadIdx.x == 0)
        atomicAdd(out, (red[0] + red[1] + red[2] + red[3]) * (1.0f / (float)NROWS));
}

extern "C" void kernel_launch(void* const* d_in, const int* in_sizes, int n_in,
                              void* d_out, int out_size, void* d_ws, size_t ws_size,
                              hipStream_t stream) {
    const float* emb = (const float*)d_in[0];
    const float* qry = (const float*)d_in[1];
    float* out = (float*)d_out;

    char* ws = (char*)d_ws;
    __hip_bfloat16* En = (__hip_bfloat16*)ws;                                  // 4 MB row-major
    __hip_bfloat16* Qn = (__hip_bfloat16*)(ws + (size_t)NROWS * DIM * 2);      // 4 MB K-major-grouped
    float* rowsum = (float*)(ws + (size_t)NROWS * DIM * 4);                    // 32 KB
    float* pickv  = rowsum + NROWS;                                            // 32 KB

    k_normalize_all<<<2 * NROWS / 4, 256, 0, stream>>>(emb, qry, En, Qn, rowsum, out);
    k_simlse<<<16 * NSPLIT, 512, 0, stream>>>(En, Qn, rowsum, pickv);
    k_finalize<<<16, 256, 0, stream>>>(rowsum, pickv, out);
}